// Round 12
// baseline (444.838 us; speedup 1.0000x reference)
//
#include <hip/hip_runtime.h>
#include <math.h>

#define CC   256
#define HW   4096
#define OC3  384
#define HID  128
#define DH   32
#define NM   4
#define NPART 32
#define SCALE 0.17677669529663688f  // 32^-0.5

typedef __bf16 bf16x8 __attribute__((ext_vector_type(8)));
typedef float  f32x4  __attribute__((ext_vector_type(4)));

__device__ __forceinline__ ushort f2bf(float x) {
    union { float f; unsigned u; } v; v.f = x;
    unsigned r = v.u + 0x7fffu + ((v.u >> 16) & 1u);   // RNE
    return (ushort)(r >> 16);
}
__device__ __forceinline__ float bf2f(ushort b) {
    union { unsigned u; float f; } v; v.u = ((unsigned)b) << 16; return v.f;
}
__device__ __forceinline__ void g2l16(const void* g, void* l) {
    __builtin_amdgcn_global_load_lds(
        (const __attribute__((address_space(1))) void*)g,
        (__attribute__((address_space(3))) void*)l, 16, 0, 0);
}

// ---------------- fused rms-norm + transpose + bf16: xnT[b][pix][c]
// float4 global loads; LDS stride 36. k_prep merged (blocks 0..383).
__global__ __launch_bounds__(256) void k_xn(const float* __restrict__ x,
        const float* __restrict__ wqkv, const float* __restrict__ g1,
        const float* __restrict__ wout,
        ushort* __restrict__ wq2t, ushort* __restrict__ woutt,
        ushort* __restrict__ xnT) {
    __shared__ float xt[256 * 36];
    __shared__ float ps[8 * 33];
    __shared__ float invn[32];
    int tid = threadIdx.x;
    if (blockIdx.x < 384) {           // merged k_prep
        int o = blockIdx.x;
        wq2t[(size_t)o * CC + tid] = f2bf(wqkv[(size_t)o * CC + tid] * g1[tid] * 16.0f);
        if (o < CC && tid < HID) woutt[(size_t)o * HID + tid] = f2bf(wout[(size_t)o * HID + tid]);
    }
    int pix0 = blockIdx.x * 32;
    int b = pix0 >> 12, hw0 = pix0 & 4095;
    int p = tid & 31, cg = tid >> 5;
    const float* xb = x + (size_t)b * CC * HW + hw0;
    {
        int cr = tid >> 3;
        int chunk = tid & 7;
        #pragma unroll
        for (int pass = 0; pass < 8; ++pass) {
            int c = pass * 32 + cr;
            float4 v = *(const float4*)&xb[(size_t)c * HW + chunk * 4];
            *(float4*)&xt[c * 36 + chunk * 4] = v;
        }
    }
    __syncthreads();
    float s = 0.f;
    #pragma unroll 8
    for (int i = 0; i < 32; ++i) { float v = xt[(cg * 32 + i) * 36 + p]; s += v * v; }
    ps[cg * 33 + p] = s;
    __syncthreads();
    if (tid < 32) {
        float t = 0.f;
        #pragma unroll
        for (int g = 0; g < 8; ++g) t += ps[g * 33 + tid];
        invn[tid] = 1.0f / fmaxf(sqrtf(t), 1e-12f);
    }
    __syncthreads();
    float inv = invn[p];
    ushort* dst = xnT + ((size_t)(pix0 + p)) * CC + cg * 32;
    #pragma unroll
    for (int q = 0; q < 4; ++q) {
        uint4 pk; ushort* o8 = (ushort*)&pk;
        #pragma unroll
        for (int i = 0; i < 8; ++i) o8[i] = f2bf(xt[(cg * 32 + q * 8 + i) * 36 + p] * inv);
        *(uint4*)&dst[q * 8] = pk;
    }
}

// ---------------- FUSED k/v GEMM + flash ctx partials. k/v never hit HBM.
// Per block (pix-tile part, batch b): dual GEMM (k,v share B tile; 32 MFMA/step),
// per-tile row max/sum from fp32 accs, exp-weighted k + raw v -> swizzled LDS
// (two 64-row phases, region aliased over GEMM staging), 32x32x128 ctx MFMA per
// head, emit raw ctx partial + (m_p, s_p). Merge in k_w2.
__global__ __launch_bounds__(256) void k_kv(const ushort* __restrict__ wq2t,
        const ushort* __restrict__ xnT, float* __restrict__ ctxp,
        float* __restrict__ mstat, float* __restrict__ sstat) {
    __shared__ __align__(16) char smem[51200];
    ushort* AsK = (ushort*)smem;                 // [2][128*32] GEMM
    ushort* AsV = (ushort*)(smem + 16384);       // [2][128*32]
    ushort* BsB = (ushort*)(smem + 32768);       // [2][128*32]
    ushort* ktile = (ushort*)smem;               // [64][128] ctx (aliases AsK)
    ushort* vtile = (ushort*)(smem + 16384);     // [64][128] (aliases AsV)
    float* mred = (float*)(smem + 49152);        // [2][128]
    float* sred = (float*)(smem + 50176);        // [2][128]
    int tid = threadIdx.x;
    int lane = tid & 63, wid = tid >> 6;
    int l15 = tid & 15, quad = (tid >> 4) & 3;
    int wm = wid >> 1, wn = wid & 1;
    int rsub = lane >> 2;
    int part = blockIdx.x & 31;
    int b    = blockIdx.x >> 5;
    int p0 = part * 128;
    const ushort* Ak = wq2t + (size_t)HID * CC;
    const ushort* Av = wq2t + (size_t)(2 * HID) * CC;
    const ushort* Bb = xnT + ((size_t)(b * HW + p0)) * CC;
    f32x4 ak[4][4], av[4][4];
    #pragma unroll
    for (int i = 0; i < 4; ++i)
        #pragma unroll
        for (int j = 0; j < 4; ++j) { ak[i][j] = (f32x4){0,0,0,0}; av[i][j] = (f32x4){0,0,0,0}; }

    auto stage = [&](int buf, int k0) {
        #pragma unroll
        for (int q = 0; q < 2; ++q) {
            int rw = wid * 32 + q * 16;
            int r  = rw + rsub;
            int sc = (lane & 3) ^ ((r >> 1) & 3);
            g2l16(Ak + (size_t)r * CC + k0 + sc * 8, &AsK[buf * 4096 + rw * 32]);
            g2l16(Av + (size_t)r * CC + k0 + sc * 8, &AsV[buf * 4096 + rw * 32]);
            g2l16(Bb + (size_t)r * CC + k0 + sc * 8, &BsB[buf * 4096 + rw * 32]);
        }
    };

    stage(0, 0);
    __syncthreads();
    #pragma unroll
    for (int s = 0; s < 8; ++s) {
        int cur = s & 1;
        if (s < 7) stage(cur ^ 1, (s + 1) * 32);
        bf16x8 afk[4], afv[4], bfr[4];
        #pragma unroll
        for (int mt = 0; mt < 4; ++mt) {
            int ra = wm * 64 + mt * 16 + l15;
            int off = cur * 4096 + ra * 32 + ((quad ^ ((ra >> 1) & 3)) << 3);
            afk[mt] = *(const bf16x8*)&AsK[off];
            afv[mt] = *(const bf16x8*)&AsV[off];
        }
        #pragma unroll
        for (int nt = 0; nt < 4; ++nt) {
            int rb = wn * 64 + nt * 16 + l15;
            bfr[nt] = *(const bf16x8*)&BsB[cur * 4096 + rb * 32 + ((quad ^ ((rb >> 1) & 3)) << 3)];
        }
        #pragma unroll
        for (int mt = 0; mt < 4; ++mt)
            #pragma unroll
            for (int nt = 0; nt < 4; ++nt) {
                ak[mt][nt] = __builtin_amdgcn_mfma_f32_16x16x32_bf16(afk[mt], bfr[nt], ak[mt][nt], 0, 0, 0);
                av[mt][nt] = __builtin_amdgcn_mfma_f32_16x16x32_bf16(afv[mt], bfr[nt], av[mt][nt], 0, 0, 0);
            }
        __syncthreads();
    }

    // ---- local row max over this wave's 64-pix half; cross-wave merge in mred
    float mloc[4][4];
    #pragma unroll
    for (int mt = 0; mt < 4; ++mt)
        #pragma unroll
        for (int r = 0; r < 4; ++r) {
            float m = ak[mt][0][r];
            #pragma unroll
            for (int nt = 1; nt < 4; ++nt) m = fmaxf(m, ak[mt][nt][r]);
            #pragma unroll
            for (int sh = 1; sh < 16; sh <<= 1) m = fmaxf(m, __shfl_xor(m, sh));
            mloc[mt][r] = m;
        }
    if (l15 == 0)
        #pragma unroll
        for (int mt = 0; mt < 4; ++mt)
            #pragma unroll
            for (int r = 0; r < 4; ++r)
                mred[wn * 128 + wm * 64 + mt * 16 + quad * 4 + r] = mloc[mt][r];
    __syncthreads();   // BAR-A: mred visible

    // ---- exp(k - mp) into ak regs; local sums -> sred
    #pragma unroll
    for (int mt = 0; mt < 4; ++mt)
        #pragma unroll
        for (int r = 0; r < 4; ++r) {
            int o = wm * 64 + mt * 16 + quad * 4 + r;
            float mp = fmaxf(mred[o], mred[128 + o]);
            float sl = 0.f;
            #pragma unroll
            for (int nt = 0; nt < 4; ++nt) {
                float e = __expf(ak[mt][nt][r] - mp);
                ak[mt][nt][r] = e;
                sl += e;
            }
            #pragma unroll
            for (int sh = 1; sh < 16; sh <<= 1) sl += __shfl_xor(sl, sh);
            if (l15 == 0) sred[wn * 128 + o] = sl;
        }
    // phase-A tile write: rows 0..63 (wm==0 waves own them)
    if (wm == 0) {
        #pragma unroll
        for (int mt = 0; mt < 4; ++mt)
            #pragma unroll
            for (int nt = 0; nt < 4; ++nt)
                #pragma unroll
                for (int r = 0; r < 4; ++r) {
                    int row = mt * 16 + quad * 4 + r;           // o = row (wm=0)
                    int pix = wn * 64 + nt * 16 + l15;
                    int boff = (row * 256 + pix * 2) ^ ((row & 7) << 4);
                    *(ushort*)((char*)ktile + boff) = f2bf(ak[mt][nt][r]);
                    *(ushort*)((char*)vtile + boff) = f2bf(av[mt][nt][r]);
                }
    }
    __syncthreads();   // BAR-B: sred + h01 tiles ready

    // ---- stats out + ctx phase 1 (waves 0,1 -> h0,h1)
    if (tid < 128) {
        float m2 = fmaxf(mred[tid], mred[128 + tid]);
        float s2 = sred[tid] + sred[128 + tid];
        int h = tid >> 5, d = tid & 31;
        size_t o = ((size_t)part * 128 + (b * 4 + h)) * 32 + d;
        mstat[o] = m2;
        sstat[o] = s2;
    }
    auto ctxPhase = [&](int hl, int h) {
        f32x4 c2[2][2];
        #pragma unroll
        for (int i = 0; i < 2; ++i)
            #pragma unroll
            for (int j = 0; j < 2; ++j) c2[i][j] = (f32x4){0,0,0,0};
        #pragma unroll
        for (int ks = 0; ks < 4; ++ks) {
            bf16x8 a2[2], b2[2];
            #pragma unroll
            for (int dt = 0; dt < 2; ++dt) {
                int row = hl * 32 + dt * 16 + l15;
                int boff = (row * 256 + (ks * 32 + quad * 8) * 2) ^ ((row & 7) << 4);
                a2[dt] = *(const bf16x8*)((char*)ktile + boff);
                b2[dt] = *(const bf16x8*)((char*)vtile + boff);
            }
            #pragma unroll
            for (int dt = 0; dt < 2; ++dt)
                #pragma unroll
                for (int et = 0; et < 2; ++et)
                    c2[dt][et] = __builtin_amdgcn_mfma_f32_16x16x32_bf16(a2[dt], b2[et], c2[dt][et], 0, 0, 0);
        }
        float* dst = ctxp + ((size_t)part * 128 + (b * 4 + h)) * 1024;
        #pragma unroll
        for (int dt = 0; dt < 2; ++dt)
            #pragma unroll
            for (int et = 0; et < 2; ++et)
                #pragma unroll
                for (int rr = 0; rr < 4; ++rr) {
                    int d = dt * 16 + quad * 4 + rr;
                    int e = et * 16 + l15;
                    dst[d * 32 + e] = c2[dt][et][rr];
                }
    };
    if (wid == 0) ctxPhase(0, 0);
    if (wid == 1) ctxPhase(1, 1);
    __syncthreads();   // BAR-C: phase-1 ctx reads done

    // ---- phase-B tile write: rows 64..127 (wm==1 waves)
    if (wm == 1) {
        #pragma unroll
        for (int mt = 0; mt < 4; ++mt)
            #pragma unroll
            for (int nt = 0; nt < 4; ++nt)
                #pragma unroll
                for (int r = 0; r < 4; ++r) {
                    int row = mt * 16 + quad * 4 + r;           // o&63 (wm=1)
                    int pix = wn * 64 + nt * 16 + l15;
                    int boff = (row * 256 + pix * 2) ^ ((row & 7) << 4);
                    *(ushort*)((char*)ktile + boff) = f2bf(ak[mt][nt][r]);
                    *(ushort*)((char*)vtile + boff) = f2bf(av[mt][nt][r]);
                }
    }
    __syncthreads();   // BAR-D: h23 tiles ready
    if (wid == 2) ctxPhase(0, 2);
    if (wid == 3) ctxPhase(1, 3);
}

// ---------------- merge flash stats (32 parts) + fold ctx into out-proj weight
__global__ __launch_bounds__(256) void k_w2(const float* __restrict__ ctxp,
        const float* __restrict__ mstat, const float* __restrict__ sstat,
        const float* __restrict__ memkv,
        const ushort* __restrict__ woutt, ushort* __restrict__ W2) {
    __shared__ ushort ctxb[4 * 32 * 40];
    __shared__ float scl[NPART][128];
    __shared__ float memsc[128][NM];
    int tid = threadIdx.x, b = blockIdx.x;
    int wid = tid >> 6;
    int l15 = tid & 15, quad = (tid >> 4) & 3;
    if (tid < 128) {
        int h = tid >> 5, d = tid & 31;
        size_t base = (size_t)(b * 4 + h) * 32 + d;
        float M = -1e30f;
        float mp[NPART];
        #pragma unroll
        for (int p = 0; p < NPART; ++p) { mp[p] = mstat[(size_t)p * 4096 + base]; M = fmaxf(M, mp[p]); }
        float mk[NM];
        #pragma unroll
        for (int m = 0; m < NM; ++m) { mk[m] = memkv[(h * DH + d) * NM + m]; M = fmaxf(M, mk[m]); }
        float Z = 0.f;
        #pragma unroll
        for (int p = 0; p < NPART; ++p) Z += sstat[(size_t)p * 4096 + base] * __expf(mp[p] - M);
        #pragma unroll
        for (int m = 0; m < NM; ++m) Z += __expf(mk[m] - M);
        float iz = 1.0f / Z;
        #pragma unroll
        for (int p = 0; p < NPART; ++p) scl[p][tid] = __expf(mp[p] - M) * iz;
        #pragma unroll
        for (int m = 0; m < NM; ++m) memsc[tid][m] = __expf(mk[m] - M) * iz;
    }
    __syncthreads();
    #pragma unroll
    for (int j = 0; j < 16; ++j) {
        int idx = tid + j * 256;            // h*1024 + d*32 + e
        int rr = idx >> 5;
        int e  = idx & 31;
        int h  = idx >> 10, d = (idx >> 5) & 31;
        float s = 0.f;
        #pragma unroll
        for (int p = 0; p < NPART; ++p)
            s += ctxp[(size_t)p * 131072 + (size_t)b * 4096 + idx] * scl[p][rr];
        #pragma unroll
        for (int m = 0; m < NM; ++m)
            s += memsc[rr][m] * memkv[512 + (h * DH + e) * NM + m];
        ctxb[(h * 32 + d) * 40 + e] = f2bf(s);
    }
    __syncthreads();
    #pragma unroll
    for (int h = 0; h < 4; ++h) {
        f32x4 acc[4][2];
        #pragma unroll
        for (int i = 0; i < 4; ++i)
            #pragma unroll
            for (int j = 0; j < 2; ++j) acc[i][j] = (f32x4){0.f, 0.f, 0.f, 0.f};
        bf16x8 af[4], bfr[2];
        #pragma unroll
        for (int mt = 0; mt < 4; ++mt)
            af[mt] = *(const bf16x8*)&woutt[(size_t)(wid * 64 + mt * 16 + l15) * HID
                                            + h * DH + quad * 8];
        #pragma unroll
        for (int nt = 0; nt < 2; ++nt)
            bfr[nt] = *(const bf16x8*)&ctxb[(h * 32 + nt * 16 + l15) * 40 + quad * 8];
        #pragma unroll
        for (int mt = 0; mt < 4; ++mt)
            #pragma unroll
            for (int nt = 0; nt < 2; ++nt)
                acc[mt][nt] = __builtin_amdgcn_mfma_f32_16x16x32_bf16(
                                  af[mt], bfr[nt], acc[mt][nt], 0, 0, 0);
        #pragma unroll
        for (int mt = 0; mt < 4; ++mt)
            #pragma unroll
            for (int nt = 0; nt < 2; ++nt)
                #pragma unroll
                for (int r = 0; r < 4; ++r) {
                    int oc = wid * 64 + mt * 16 + quad * 4 + r;
                    int d  = nt * 16 + l15;
                    W2[((size_t)b * CC + oc) * HID + h * DH + d] = f2bf(acc[mt][nt][r]);
                }
    }
}

// ---------------- final: q computed in-block (Wq @ xnT tile) -> softmax on fp32
// accs -> W2 GEMM -> bias + rms*g2.
__global__ __launch_bounds__(256) void k_final(const ushort* __restrict__ xnT,
        const ushort* __restrict__ wq2t, const ushort* __restrict__ W2,
        const float* __restrict__ bout, const float* __restrict__ g2,
        float* __restrict__ y) {
    __shared__ __align__(16) char smem[52224];
    ushort* xnTs = (ushort*)smem;              // [64][128]
    float*  red  = (float*)smem;               // aliases xnTs
    float*  invs = (float*)(smem + 4352);
    ushort* Qw   = (ushort*)(smem + 16384);    // [2][128*32]; aliased as WsQ
    ushort* sq   = (ushort*)(smem + 32768);    // [64][136]
    float*  bl   = (float*)(smem + 50176);
    float*  gl   = (float*)(smem + 51200);
    int tid = threadIdx.x;
    int b = blockIdx.y;
    int hwb = blockIdx.x * 64;
    int lane = tid & 63, wid = tid >> 6;
    int l15 = tid & 15, quad = (tid >> 4) & 3;
    int rsub = lane >> 2;
    bl[tid] = bout[tid];
    gl[tid] = g2[tid];

    auto stageX = [&](int half) {
        const ushort* xb = xnT + ((size_t)(b * HW + hwb)) * CC + half * 128;
        #pragma unroll
        for (int qq = 0; qq < 4; ++qq) {
            int r0 = qq * 16 + wid * 4;
            int r  = r0 + (lane >> 4);
            int g  = (lane & 15) ^ (r & 7);
            g2l16(xb + (size_t)r * CC + g * 8, &xnTs[r0 * 128]);
        }
    };
    auto stageQ = [&](int buf, int k0) {
        #pragma unroll
        for (int qq = 0; qq < 2; ++qq) {
            int rw = wid * 32 + qq * 16;
            int r  = rw + rsub;
            int sc = (lane & 3) ^ ((r >> 1) & 3);
            g2l16(wq2t + (size_t)r * CC + k0 + sc * 8, &Qw[buf * 4096 + rw * 32]);
        }
    };

    f32x4 accq[2][4];
    #pragma unroll
    for (int i = 0; i < 2; ++i)
        #pragma unroll
        for (int j = 0; j < 4; ++j) accq[i][j] = (f32x4){0.f, 0.f, 0.f, 0.f};
    stageX(0);
    stageQ(0, 0);
    __syncthreads();
    #pragma unroll
    for (int s = 0; s < 8; ++s) {
        int cur = s & 1;
        if (s < 7 && s != 3) stageQ(cur ^ 1, (s + 1) * 32);
        bf16x8 af[2], bfr[4];
        #pragma unroll
        for (int mt = 0; mt < 2; ++mt) {
            int ra = wid * 32 + mt * 16 + l15;
            af[mt] = *(const bf16x8*)&Qw[cur * 4096 + ra * 32 + ((quad ^ ((ra >> 1) & 3)) << 3)];
        }
        int cread = (s & 3) * 4 + quad;
        #pragma unroll
        for (int nt = 0; nt < 4; ++nt) {
            int rb = nt * 16 + l15;
            bfr[nt] = *(const bf16x8*)&xnTs[rb * 128 + ((cread ^ (rb & 7)) << 3)];
        }
        #pragma unroll
        for (int mt = 0; mt < 2; ++mt)
            #pragma unroll
            for (int nt = 0; nt < 4; ++nt)
                accq[mt][nt] = __builtin_amdgcn_mfma_f32_16x16x32_bf16(
                                   af[mt], bfr[nt], accq[mt][nt], 0, 0, 0);
        if (s == 3) {
            __syncthreads();
            stageX(1);
            stageQ(cur ^ 1, 128);
        }
        __syncthreads();
    }

    #pragma unroll
    for (int nt = 0; nt < 4; ++nt) {
        float m = -1e30f;
        #pragma unroll
        for (int mt = 0; mt < 2; ++mt)
            #pragma unroll
            for (int r = 0; r < 4; ++r) m = fmaxf(m, accq[mt][nt][r]);
        m = fmaxf(m, __shfl_xor(m, 16));
        m = fmaxf(m, __shfl_xor(m, 32));
        float s = 0.f;
        float e[2][4];
        #pragma unroll
        for (int mt = 0; mt < 2; ++mt)
            #pragma unroll
            for (int r = 0; r < 4; ++r) { e[mt][r] = __expf(accq[mt][nt][r] - m); s += e[mt][r]; }
        s += __shfl_xor(s, 16);
        s += __shfl_xor(s, 32);
        float r_ = SCALE / s;
        int pix = nt * 16 + l15;
        #pragma unroll
        for (int mt = 0; mt < 2; ++mt)
            #pragma unroll
            for (int r = 0; r < 4; ++r)
                sq[pix * 136 + wid * 32 + mt * 16 + quad * 4 + r] = f2bf(e[mt][r] * r_);
    }

    ushort* WsQ = Qw;
    f32x4 acc[4][4];
    #pragma unroll
    for (int i = 0; i < 4; ++i)
        #pragma unroll
        for (int j = 0; j < 4; ++j) acc[i][j] = (f32x4){0.f, 0.f, 0.f, 0.f};
    const ushort* W2b = W2 + (size_t)b * CC * HID;
    for (int k0 = 0; k0 < HID; k0 += 32) {
        __syncthreads();
        #pragma unroll
        for (int q = 0; q < 4; ++q) {
            int rw = wid * 64 + q * 16;
            int r  = rw + rsub;
            int sc = (lane & 3) ^ ((r >> 1) & 3);
            g2l16(W2b + (size_t)r * HID + k0 + sc * 8, &WsQ[rw * 32]);
        }
        __syncthreads();
        bf16x8 af[4], bfr[4];
        #pragma unroll
        for (int mt = 0; mt < 4; ++mt) {
            int ra = wid * 64 + mt * 16 + l15;
            af[mt] = *(const bf16x8*)&WsQ[ra * 32 + ((quad ^ ((ra >> 1) & 3)) << 3)];
        }
        #pragma unroll
        for (int nt = 0; nt < 4; ++nt)
            bfr[nt] = *(const bf16x8*)&sq[(nt * 16 + l15) * 136 + k0 + quad * 8];
        #pragma unroll
        for (int mt = 0; mt < 4; ++mt)
            #pragma unroll
            for (int nt = 0; nt < 4; ++nt)
                acc[mt][nt] = __builtin_amdgcn_mfma_f32_16x16x32_bf16(
                                  af[mt], bfr[nt], acc[mt][nt], 0, 0, 0);
    }

    float part[4] = {0.f, 0.f, 0.f, 0.f};
    #pragma unroll
    for (int mt = 0; mt < 4; ++mt)
        #pragma unroll
        for (int r = 0; r < 4; ++r) {
            int oc = wid * 64 + mt * 16 + quad * 4 + r;
            float bo = bl[oc];
            #pragma unroll
            for (int nt = 0; nt < 4; ++nt) {
                float v = acc[mt][nt][r] + bo;
                acc[mt][nt][r] = v;
                part[nt] += v * v;
            }
        }
    __syncthreads();
    #pragma unroll
    for (int nt = 0; nt < 4; ++nt)
        red[(nt * 16 + l15) * 17 + wid * 4 + quad] = part[nt];
    __syncthreads();
    if (tid < 64) {
        float s = 0.f;
        #pragma unroll
        for (int g = 0; g < 16; ++g) s += red[tid * 17 + g];
        invs[tid] = 1.0f / fmaxf(sqrtf(s), 1e-12f);
    }
    __syncthreads();
    #pragma unroll
    for (int mt = 0; mt < 4; ++mt)
        #pragma unroll
        for (int nt = 0; nt < 4; ++nt) {
            int pix = nt * 16 + l15;
            float iv = invs[pix];
            #pragma unroll
            for (int r = 0; r < 4; ++r) {
                int oc = wid * 64 + mt * 16 + quad * 4 + r;
                y[((size_t)(b * CC + oc)) * HW + hwb + pix] = acc[mt][nt][r] * iv * gl[oc] * 16.0f;
            }
        }
}

extern "C" void kernel_launch(void* const* d_in, const int* in_sizes, int n_in,
                              void* d_out, int out_size, void* d_ws, size_t ws_size,
                              hipStream_t stream) {
    const float* x     = (const float*)d_in[0];
    const float* g1    = (const float*)d_in[1];
    const float* memkv = (const float*)d_in[2];
    const float* wqkv  = (const float*)d_in[3];
    const float* wout  = (const float*)d_in[4];
    const float* bout  = (const float*)d_in[5];
    const float* g2    = (const float*)d_in[6];
    float* y = (float*)d_out;

    char* w = (char*)d_ws;
    ushort* wq2t  = (ushort*)w;  w += (size_t)OC3 * CC * 2;
    ushort* woutt = (ushort*)w;  w += (size_t)CC * HID * 2;
    float*  mstat = (float*)w;   w += (size_t)NPART * 4096 * 4;   // 512 KB
    float*  sstat = (float*)w;   w += (size_t)NPART * 4096 * 4;   // 512 KB
    float*  ctxp  = (float*)w;   w += (size_t)NPART * 131072 * 4; // 16 MB
    ushort* W2    = (ushort*)w;  w += (size_t)32 * CC * HID * 2;  // 2 MB
    ushort* xnT   = (ushort*)w;  w += (size_t)32 * HW * CC * 2;   // 67 MB

    k_xn    <<<dim3(4096),      dim3(256), 0, stream>>>(x, wqkv, g1, wout, wq2t, woutt, xnT);
    k_kv    <<<dim3(1024),      dim3(256), 0, stream>>>(wq2t, xnT, ctxp, mstat, sstat);
    k_w2    <<<dim3(32),        dim3(256), 0, stream>>>(ctxp, mstat, sstat, memkv, woutt, W2);
    k_final <<<dim3(64, 32),    dim3(256), 0, stream>>>(xnT, wq2t, W2, bout, g2, y);
}